// Round 4
// baseline (256.332 us; speedup 1.0000x reference)
//
#include <hip/hip_runtime.h>
#include <math.h>

#define KNN_EPS 1e-8f
// Spatial grid: domain [0,256)^3, cell h=16 -> 16^3 = 4096 cells.
#define GH 16.0f
#define GC 16
#define NCELLS (GC * GC * GC)
#define MARGIN 1.0f   // >> max |noisy_d - true_d| (~0.05) -> safe pruning
#define CAPR 16       // ref bucket slots/cell. Poisson(4.88): P(>16)~1e-5 ->
                      // ~0.05 expected spilled refs/run; spills go to the
                      // global refspill list evaluated by every query (same
                      // candidate union -> bit-identical; harness-proven r17).
                      // rbuck = 4096*16*16B = 1 MB: L2-resident.

// ---------------------------------------------------------------------------
// Validated arithmetic (round 8, absmax 0.0547):
//   rsq/qsq: non-fused sequential squares; t: asc FMA chain;
//   d = max(fma(-2,t,fl(qsq+rsq)), 0); epilogue: +eps, IEEE div, seq sums.
// Selection: (d, idx) lexicographic min-3 -- order-independent, bit-identical
// across r10-r18 restructures (scan order is harmless).
// DO NOT change roundings -- only execution structure.
//
// r18: r17's data design was right (qbuck deleted, CAPR=16, query recompute;
// FETCH fell to 12MB) but its implementation spilled to scratch: WRITE_SIZE
// 60MB on a kernel that writes 640KB of out == private-segment round-trips
// (es[] array + slab guards at VGPR_Count=28). r18 removes every array, all
// LDS, all barriers: named-register state only, cell indices derived
// arithmetically (const-div), 4 threads/query merged with a 2-round
// __shfl_xor butterfly (INF-guarded lex insert), candidate loads in
// unconditional 64B line-granule groups of 4 (eval predicated on count).
// ---------------------------------------------------------------------------

__device__ __forceinline__ int cell_coord(float v) {
    int c = (int)floorf(v * (1.0f / GH));
    return min(max(c, 0), GC - 1);
}

// Scatter ONLY the reference points (20k) into compact buckets.
__global__ void scatter_ref_kernel(
    const float* __restrict__ xyz1, int n1,
    int* __restrict__ counts,
    float4* __restrict__ rbuck,
    float4* __restrict__ refspill, int* __restrict__ rsn)
{
#pragma clang fp contract(off)
    int i = blockIdx.x * blockDim.x + threadIdx.x;
    if (i >= n1) return;
    float x = xyz1[3 * i + 0];
    float y = xyz1[3 * i + 1];
    float z = xyz1[3 * i + 2];
    int cid = (cell_coord(z) * GC + cell_coord(y)) * GC + cell_coord(x);
    int pos = atomicAdd(&counts[cid], 1);
    float4 v = make_float4(x, y, z, __int_as_float(i));
    if (pos < CAPR) rbuck[cid * CAPR + pos] = v;
    else { int sp = atomicAdd(rsn, 1); refspill[sp] = v; }
}

// (d, idx)-lexicographic insert: order-independent == validated stable scan.
__device__ __forceinline__ void top3_insert_lex(float d, int j,
                                                float& bd0, float& bd1, float& bd2,
                                                int& bi0, int& bi1, int& bi2) {
    if (d < bd2 || (d == bd2 && j < bi2)) {
        if (d < bd1 || (d == bd1 && j < bi1)) {
            bd2 = bd1; bi2 = bi1;
            if (d < bd0 || (d == bd0 && j < bi0)) {
                bd1 = bd0; bi1 = bi0;
                bd0 = d;   bi0 = j;
            } else {
                bd1 = d;   bi1 = j;
            }
        } else {
            bd2 = d;       bi2 = j;
        }
    }
}

// Validated candidate evaluation (round 8 roundings, rsq recomputed bit-equal)
__device__ __forceinline__ void eval_candidate(
    float4 r, float qx, float qy, float qz, float qsq,
    float& bd0, float& bd1, float& bd2, int& bi0, int& bi1, int& bi2) {
    int ridx = __float_as_int(r.w);
    float rsq = r.x * r.x + r.y * r.y;
    rsq = rsq + r.z * r.z;
    float t = fmaf(qz, r.z, fmaf(qy, r.y, qx * r.x));
    float h = qsq + rsq;
    float d = fmaxf(fmaf(-2.0f, t, h), 0.0f);
    top3_insert_lex(d, ridx, bd0, bd1, bd2, bi0, bi1, bi2);
}

// Rigorous certification radius after scanning cell-rings <= rho.
__device__ __forceinline__ float cert_radius(float qx, float qy, float qz,
                                             int icx, int icy, int icz, int rho) {
    float R = INFINITY;
    if (icx - rho > 0)      R = fminf(R, qx - (float)(icx - rho) * GH);
    if (icx + rho < GC - 1) R = fminf(R, (float)(icx + rho + 1) * GH - qx);
    if (icy - rho > 0)      R = fminf(R, qy - (float)(icy - rho) * GH);
    if (icy + rho < GC - 1) R = fminf(R, (float)(icy + rho + 1) * GH - qy);
    if (icz - rho > 0)      R = fminf(R, qz - (float)(icz - rho) * GH);
    if (icz + rho < GC - 1) R = fminf(R, (float)(icz + rho + 1) * GH - qz);
    return R;
}

// Validated epilogue (round 8) -> writes out[qid]
__device__ __forceinline__ void epilogue_store(
    float bd0, float bd1, float bd2, int bi0, int bi1, int bi2,
    int qid, int C, const float* __restrict__ point1, float* __restrict__ out) {
#pragma clang fp contract(off)
    float dd0 = bd0 + KNN_EPS;
    float dd1 = bd1 + KNN_EPS;
    float dd2 = bd2 + KNN_EPS;
    float w0 = 1.0f / dd0;
    float w1 = 1.0f / dd1;
    float w2 = 1.0f / dd2;
    float s  = w0 + w1;
    s = s + w2;
    float m = fmaxf(s, 3.0f);
    w0 = w0 / m;
    w1 = w1 / m;
    w2 = w2 / m;
    const int c = qid - (qid / C) * C;
    float p0 = point1[bi0 * C + c];
    float p1 = point1[bi1 * C + c];
    float p2 = point1[bi2 * C + c];
    float acc = w0 * p0 + w1 * p1;
    acc = acc + w2 * p2;
    out[qid] = acc;
}

// r18 search: 4 THREADS per query (slab = gt&3), each scans 7 of the 27
// neighbor cells (slab 3: 6 cells + the refspill list). No LDS, no arrays,
// no barriers -- named registers only. Candidate loads are unconditional
// 64B groups of 4 slots (always inside the cell's 16-slot row); evaluation
// predicated on the real count. Partials merged with a 2-round __shfl_xor
// butterfly (lanes 4k..4k+3 belong to one query) using the validated
// INF-guarded lexicographic insert; all 4 lanes converge to the same top-3,
// lane (gt&3)==0 runs cert / rare fallback / epilogue.
__global__ __launch_bounds__(256, 4) void knn_query_kernel(
    const float* __restrict__ xyz2,
    const float* __restrict__ motion,
    const float4* __restrict__ rbuck,
    const int*   __restrict__ counts,
    const float4* __restrict__ refspill,
    const int*   __restrict__ rsn,
    const float* __restrict__ point1,
    float* __restrict__ out,
    int nq, int C)
{
#pragma clang fp contract(off)
    const int gt   = blockIdx.x * 256 + threadIdx.x;
    const int qi   = gt >> 2;
    const int slab = gt & 3;
    const bool active = qi < nq;
    const int i = active ? qi : 0;
    const int n = i / C;

    // bit-identical query recompute (validated adds, contract off)
    const float qx = xyz2[3 * n + 0] + motion[3 * i + 0];
    const float qy = xyz2[3 * n + 1] + motion[3 * i + 1];
    const float qz = xyz2[3 * n + 2] + motion[3 * i + 2];
    float qsq = qx * qx + qy * qy;
    qsq = qsq + qz * qz;

    const int icx = cell_coord(qx);
    const int icy = cell_coord(qy);
    const int icz = cell_coord(qz);

    float bd0 = INFINITY, bd1 = INFINITY, bd2 = INFINITY;
    int   bi0 = 0,        bi1 = 0,        bi2 = 0;

    // --- prep: my 7 cells' (cid, count) in named registers; the 7 counts
    //     loads have no mutual deps -> issued back-to-back (one window) ---
#define CELL_PREP(rr, eV, cidV)                                               \
    {                                                                          \
        int r = slab * 7 + (rr);                                               \
        int d9 = r / 9;                                                        \
        int rem = r - 9 * d9;                                                  \
        int d3 = rem / 3;                                                      \
        int dxv = rem - 3 * d3;                                                \
        int cz = icz + d9 - 1, cy = icy + d3 - 1, cx = icx + dxv - 1;          \
        bool ok = (r < 27) && ((unsigned)cz < GC) && ((unsigned)cy < GC) &&    \
                  ((unsigned)cx < GC);                                         \
        cidV = ok ? (cz * GC + cy) * GC + cx : 0;                              \
        eV = ok ? min(counts[cidV], CAPR) : 0;                                 \
    }

    int e0, e1, e2, e3, e4, e5, e6;
    int c0, c1, c2, c3, c4, c5, c6;
    CELL_PREP(0, e0, c0)
    CELL_PREP(1, e1, c1)
    CELL_PREP(2, e2, c2)
    CELL_PREP(3, e3, c3)
    CELL_PREP(4, e4, c4)
    CELL_PREP(5, e5, c5)
    CELL_PREP(6, e6, c6)
#undef CELL_PREP

    // --- scan: unconditional 64B group loads, predicated evals ---
#define CELL_SCAN(eV, cidV)                                                    \
    {                                                                          \
        const float4* __restrict__ cp = rbuck + (cidV) * CAPR;                 \
        for (int s = 0; s < (eV); s += 4) {                                    \
            float4 a0 = cp[s + 0];                                             \
            float4 a1 = cp[s + 1];                                             \
            float4 a2 = cp[s + 2];                                             \
            float4 a3 = cp[s + 3];                                             \
            eval_candidate(a0, qx, qy, qz, qsq, bd0, bd1, bd2, bi0, bi1, bi2); \
            if (s + 1 < (eV))                                                  \
                eval_candidate(a1, qx, qy, qz, qsq, bd0, bd1, bd2, bi0, bi1, bi2); \
            if (s + 2 < (eV))                                                  \
                eval_candidate(a2, qx, qy, qz, qsq, bd0, bd1, bd2, bi0, bi1, bi2); \
            if (s + 3 < (eV))                                                  \
                eval_candidate(a3, qx, qy, qz, qsq, bd0, bd1, bd2, bi0, bi1, bi2); \
        }                                                                      \
    }

    CELL_SCAN(e0, c0)
    CELL_SCAN(e1, c1)
    CELL_SCAN(e2, c2)
    CELL_SCAN(e3, c3)
    CELL_SCAN(e4, c4)
    CELL_SCAN(e5, c5)
    CELL_SCAN(e6, c6)
#undef CELL_SCAN

    // slab 3 also evaluates the global refspill list (~always empty)
    if (slab == 3) {
        const int rspn = *rsn;
        for (int k = 0; k < rspn; ++k)
            eval_candidate(refspill[k], qx, qy, qz, qsq,
                           bd0, bd1, bd2, bi0, bi1, bi2);
    }

    // --- butterfly merge across the query's 4 lanes (register-only) ---
#define MERGE_XOR(mask)                                                        \
    {                                                                          \
        float od0 = __shfl_xor(bd0, mask); int oi0 = __shfl_xor(bi0, mask);    \
        float od1 = __shfl_xor(bd1, mask); int oi1 = __shfl_xor(bi1, mask);    \
        float od2 = __shfl_xor(bd2, mask); int oi2 = __shfl_xor(bi2, mask);    \
        if (od0 < INFINITY)                                                    \
            top3_insert_lex(od0, oi0, bd0, bd1, bd2, bi0, bi1, bi2);           \
        if (od1 < INFINITY)                                                    \
            top3_insert_lex(od1, oi1, bd0, bd1, bd2, bi0, bi1, bi2);           \
        if (od2 < INFINITY)                                                    \
            top3_insert_lex(od2, oi2, bd0, bd1, bd2, bi0, bi1, bi2);           \
    }
    MERGE_XOR(1)
    MERGE_XOR(2)
#undef MERGE_XOR

    if (slab == 0 && active) {
        // Certified after full rho<=1 ring (+spill); fallback ~1e-6.
        float R = cert_radius(qx, qy, qz, icx, icy, icz, 1);
        if (!(bd2 + MARGIN <= R * R)) {
            for (int rho = 2; rho < GC; ++rho) {
                for (int dz = -rho; dz <= rho; ++dz) {
                    int cz = icz + dz;
                    if (cz < 0 || cz >= GC) continue;
                    int adz = (dz < 0) ? -dz : dz;
                    for (int dy = -rho; dy <= rho; ++dy) {
                        int cy = icy + dy;
                        if (cy < 0 || cy >= GC) continue;
                        int ady = (dy < 0) ? -dy : dy;
                        int step = (adz == rho || ady == rho) ? 1 : 2 * rho;
                        for (int dx = -rho; dx <= rho; dx += step) {
                            int cx = icx + dx;
                            if (cx < 0 || cx >= GC) continue;
                            int cid = (cz * GC + cy) * GC + cx;
                            int e = min(counts[cid], CAPR);
                            for (int s = 0; s < e; ++s)
                                eval_candidate(rbuck[cid * CAPR + s],
                                               qx, qy, qz, qsq,
                                               bd0, bd1, bd2, bi0, bi1, bi2);
                        }
                    }
                }
                float Rr = cert_radius(qx, qy, qz, icx, icy, icz, rho);
                if (bd2 + MARGIN <= Rr * Rr) break;
            }
        }
        epilogue_store(bd0, bd1, bd2, bi0, bi1, bi2, qi, C, point1, out);
    }
}

extern "C" void kernel_launch(void* const* d_in, const int* in_sizes, int n_in,
                              void* d_out, int out_size, void* d_ws, size_t ws_size,
                              hipStream_t stream) {
    const float* xyz1   = (const float*)d_in[0];
    const float* point1 = (const float*)d_in[1];
    const float* xyz2   = (const float*)d_in[2];
    const float* motion = (const float*)d_in[3];
    float* out = (float*)d_out;

    const int n1 = in_sizes[0] / 3;
    const int n2 = in_sizes[2] / 3;
    const int C  = in_sizes[1] / n1;
    const int nq = n2 * C;

    // ws layout (~1.4 MB): rbuck | refspill | zero-zone(counts, rsn)
    char* ws = (char*)d_ws;
    size_t off = 0;
    auto alloc = [&](size_t bytes) {
        char* p = ws + off;
        off = (off + bytes + 255) & ~(size_t)255;
        return p;
    };
    float4* rbuck    = (float4*)alloc((size_t)NCELLS * CAPR * 16);
    float4* refspill = (float4*)alloc((size_t)n1 * 16);
    int*    zero     = (int*)alloc((size_t)(NCELLS + 1) * 4);
    int* counts = zero;
    int* rsn    = zero + NCELLS;

    hipMemsetAsync(zero, 0, (size_t)(NCELLS + 1) * 4, stream);
    scatter_ref_kernel<<<(n1 + 255) / 256, 256, 0, stream>>>(
        xyz1, n1, counts, rbuck, refspill, rsn);
    const int nthreads = nq * 4;
    knn_query_kernel<<<(nthreads + 255) / 256, 256, 0, stream>>>(
        xyz2, motion, rbuck, counts, refspill, rsn, point1, out, nq, C);
}

// Round 5
// 214.523 us; speedup vs baseline: 1.1949x; 1.1949x over previous
//
#include <hip/hip_runtime.h>
#include <math.h>

#define KNN_EPS 1e-8f
// Spatial grid: domain [0,256)^3, cell h=16 -> 16^3 = 4096 cells.
#define GH 16.0f
#define GC 16
#define NCELLS (GC * GC * GC)
#define MARGIN 1.0f   // >> max |noisy_d - true_d| (~0.05) -> safe pruning
#define CAPR 16       // ref bucket slots/cell. Poisson(4.88): P(>16)~1e-5 ->
                      // ~0.05 expected spilled refs/run; spills go to the
                      // global refspill list evaluated by every query (same
                      // candidate union -> bit-identical; harness-proven
                      // r17/r18, absmax 0.0547). rbuck = 1 MB: L2-resident.

// ---------------------------------------------------------------------------
// Validated arithmetic (round 8, absmax 0.0547):
//   rsq/qsq: non-fused sequential squares; t: asc FMA chain;
//   d = max(fma(-2,t,fl(qsq+rsq)), 0); epilogue: +eps, IEEE div, seq sums.
// Selection: (d, idx) lexicographic min-3 -- order-independent, bit-identical
// across r10-r19 restructures (scan order is harmless).
// DO NOT change roundings -- only execution structure.
//
// r19 diagnosis of r17/r18 (161/198us, WRITE_SIZE 55-60MB, VGPR_Count 28):
// __launch_bounds__(256,4)'s min-waves arg CAPPED the register allocator
// below the ~45 live values of the 4-slab structure -> per-thread scratch
// spills -> 55MB of HBM scratch round-trips. The structure was never truly
// measured. r19: simplest per-thread form, UNCAPPED allocator
// (__launch_bounds__(256) only), z-plane-batched count loads (3 latency
// windows, not 27), unconditional 64B line loads + predicated evals.
// No LDS / shuffles / barriers / slabs.
// ---------------------------------------------------------------------------

__device__ __forceinline__ int cell_coord(float v) {
    int c = (int)floorf(v * (1.0f / GH));
    return min(max(c, 0), GC - 1);
}

// Scatter ONLY the reference points (20k) into compact buckets.
__global__ void scatter_ref_kernel(
    const float* __restrict__ xyz1, int n1,
    int* __restrict__ counts,
    float4* __restrict__ rbuck,
    float4* __restrict__ refspill, int* __restrict__ rsn)
{
#pragma clang fp contract(off)
    int i = blockIdx.x * blockDim.x + threadIdx.x;
    if (i >= n1) return;
    float x = xyz1[3 * i + 0];
    float y = xyz1[3 * i + 1];
    float z = xyz1[3 * i + 2];
    int cid = (cell_coord(z) * GC + cell_coord(y)) * GC + cell_coord(x);
    int pos = atomicAdd(&counts[cid], 1);
    float4 v = make_float4(x, y, z, __int_as_float(i));
    if (pos < CAPR) rbuck[cid * CAPR + pos] = v;
    else { int sp = atomicAdd(rsn, 1); refspill[sp] = v; }
}

// (d, idx)-lexicographic insert: order-independent == validated stable scan.
__device__ __forceinline__ void top3_insert_lex(float d, int j,
                                                float& bd0, float& bd1, float& bd2,
                                                int& bi0, int& bi1, int& bi2) {
    if (d < bd2 || (d == bd2 && j < bi2)) {
        if (d < bd1 || (d == bd1 && j < bi1)) {
            bd2 = bd1; bi2 = bi1;
            if (d < bd0 || (d == bd0 && j < bi0)) {
                bd1 = bd0; bi1 = bi0;
                bd0 = d;   bi0 = j;
            } else {
                bd1 = d;   bi1 = j;
            }
        } else {
            bd2 = d;       bi2 = j;
        }
    }
}

// Validated candidate evaluation (round 8 roundings, rsq recomputed bit-equal)
__device__ __forceinline__ void eval_candidate(
    float4 r, float qx, float qy, float qz, float qsq,
    float& bd0, float& bd1, float& bd2, int& bi0, int& bi1, int& bi2) {
    int ridx = __float_as_int(r.w);
    float rsq = r.x * r.x + r.y * r.y;
    rsq = rsq + r.z * r.z;
    float t = fmaf(qz, r.z, fmaf(qy, r.y, qx * r.x));
    float h = qsq + rsq;
    float d = fmaxf(fmaf(-2.0f, t, h), 0.0f);
    top3_insert_lex(d, ridx, bd0, bd1, bd2, bi0, bi1, bi2);
}

// Rigorous certification radius after scanning cell-rings <= rho.
__device__ __forceinline__ float cert_radius(float qx, float qy, float qz,
                                             int icx, int icy, int icz, int rho) {
    float R = INFINITY;
    if (icx - rho > 0)      R = fminf(R, qx - (float)(icx - rho) * GH);
    if (icx + rho < GC - 1) R = fminf(R, (float)(icx + rho + 1) * GH - qx);
    if (icy - rho > 0)      R = fminf(R, qy - (float)(icy - rho) * GH);
    if (icy + rho < GC - 1) R = fminf(R, (float)(icy + rho + 1) * GH - qy);
    if (icz - rho > 0)      R = fminf(R, qz - (float)(icz - rho) * GH);
    if (icz + rho < GC - 1) R = fminf(R, (float)(icz + rho + 1) * GH - qz);
    return R;
}

// Validated epilogue (round 8) -> writes out[qid]
__device__ __forceinline__ void epilogue_store(
    float bd0, float bd1, float bd2, int bi0, int bi1, int bi2,
    int qid, int C, const float* __restrict__ point1, float* __restrict__ out) {
#pragma clang fp contract(off)
    float dd0 = bd0 + KNN_EPS;
    float dd1 = bd1 + KNN_EPS;
    float dd2 = bd2 + KNN_EPS;
    float w0 = 1.0f / dd0;
    float w1 = 1.0f / dd1;
    float w2 = 1.0f / dd2;
    float s  = w0 + w1;
    s = s + w2;
    float m = fmaxf(s, 3.0f);
    w0 = w0 / m;
    w1 = w1 / m;
    w2 = w2 / m;
    const int c = qid - (qid / C) * C;
    float p0 = point1[bi0 * C + c];
    float p1 = point1[bi1 * C + c];
    float p2 = point1[bi2 * C + c];
    float acc = w0 * p0 + w1 * p1;
    acc = acc + w2 * p2;
    out[qid] = acc;
}

// r19 search: ONE THREAD per query. Uncapped register allocator
// (__launch_bounds__ block-size only). The 27-hood is scanned one z-plane
// (9 cells) at a time: 9 independent count loads issued back-to-back (one
// latency window), then per-cell unconditional 64B groups of 4 slots
// (always inside the CAPR=16 row) with count-predicated evals -> 4-deep MLP.
// Named registers only; no LDS, no shuffles, no barriers.
__global__ __launch_bounds__(256) void knn_query_kernel(
    const float* __restrict__ xyz2,
    const float* __restrict__ motion,
    const float4* __restrict__ rbuck,
    const int*   __restrict__ counts,
    const float4* __restrict__ refspill,
    const int*   __restrict__ rsn,
    const float* __restrict__ point1,
    float* __restrict__ out,
    int nq, int C)
{
#pragma clang fp contract(off)
    const int qi = blockIdx.x * 256 + threadIdx.x;
    if (qi >= nq) return;
    const int n = qi / C;

    // bit-identical query recompute (validated adds, contract off)
    const float qx = xyz2[3 * n + 0] + motion[3 * qi + 0];
    const float qy = xyz2[3 * n + 1] + motion[3 * qi + 1];
    const float qz = xyz2[3 * n + 2] + motion[3 * qi + 2];
    float qsq = qx * qx + qy * qy;
    qsq = qsq + qz * qz;

    const int icx = cell_coord(qx);
    const int icy = cell_coord(qy);
    const int icz = cell_coord(qz);

    float bd0 = INFINITY, bd1 = INFINITY, bd2 = INFINITY;
    int   bi0 = 0,        bi1 = 0,        bi2 = 0;

    // J is a literal 0..8 -> /3 and %3 fold at compile time.
#define PREP9(J, eV, cidV)                                                     \
    {                                                                          \
        int cy = icy + (J) / 3 - 1;                                            \
        int cx = icx + (J) % 3 - 1;                                            \
        bool ok = okz && ((unsigned)cy < GC) && ((unsigned)cx < GC);           \
        cidV = ok ? (czbase + cy) * GC + cx : 0;                               \
        eV = ok ? min(counts[cidV], CAPR) : 0;                                 \
    }

#define SCAN1(eV, cidV)                                                        \
    {                                                                          \
        const float4* __restrict__ cp = rbuck + (cidV) * CAPR;                 \
        for (int s = 0; s < (eV); s += 4) {                                    \
            float4 a0 = cp[s + 0];                                             \
            float4 a1 = cp[s + 1];                                             \
            float4 a2 = cp[s + 2];                                             \
            float4 a3 = cp[s + 3];                                             \
            eval_candidate(a0, qx, qy, qz, qsq, bd0, bd1, bd2, bi0, bi1, bi2); \
            if (s + 1 < (eV))                                                  \
                eval_candidate(a1, qx, qy, qz, qsq,                            \
                               bd0, bd1, bd2, bi0, bi1, bi2);                  \
            if (s + 2 < (eV))                                                  \
                eval_candidate(a2, qx, qy, qz, qsq,                            \
                               bd0, bd1, bd2, bi0, bi1, bi2);                  \
            if (s + 3 < (eV))                                                  \
                eval_candidate(a3, qx, qy, qz, qsq,                            \
                               bd0, bd1, bd2, bi0, bi1, bi2);                  \
        }                                                                      \
    }

    for (int pz = 0; pz < 3; ++pz) {
        const int cz = icz + pz - 1;
        const bool okz = ((unsigned)cz < GC);
        const int czbase = cz * GC;

        int e0, e1, e2, e3, e4, e5, e6, e7, e8;
        int c0, c1, c2, c3, c4, c5, c6, c7, c8;
        PREP9(0, e0, c0)
        PREP9(1, e1, c1)
        PREP9(2, e2, c2)
        PREP9(3, e3, c3)
        PREP9(4, e4, c4)
        PREP9(5, e5, c5)
        PREP9(6, e6, c6)
        PREP9(7, e7, c7)
        PREP9(8, e8, c8)

        SCAN1(e0, c0)
        SCAN1(e1, c1)
        SCAN1(e2, c2)
        SCAN1(e3, c3)
        SCAN1(e4, c4)
        SCAN1(e5, c5)
        SCAN1(e6, c6)
        SCAN1(e7, c7)
        SCAN1(e8, c8)
    }
#undef PREP9
#undef SCAN1

    // global refspill list (~always empty; union validated r17/r18)
    const int rspn = *rsn;
    for (int k = 0; k < rspn; ++k)
        eval_candidate(refspill[k], qx, qy, qz, qsq,
                       bd0, bd1, bd2, bi0, bi1, bi2);

    // Certified after full rho<=1 ring (+spill); fallback ~1e-6.
    float R = cert_radius(qx, qy, qz, icx, icy, icz, 1);
    if (!(bd2 + MARGIN <= R * R)) {
        for (int rho = 2; rho < GC; ++rho) {
            for (int dz = -rho; dz <= rho; ++dz) {
                int cz = icz + dz;
                if (cz < 0 || cz >= GC) continue;
                int adz = (dz < 0) ? -dz : dz;
                for (int dy = -rho; dy <= rho; ++dy) {
                    int cy = icy + dy;
                    if (cy < 0 || cy >= GC) continue;
                    int ady = (dy < 0) ? -dy : dy;
                    int step = (adz == rho || ady == rho) ? 1 : 2 * rho;
                    for (int dx = -rho; dx <= rho; dx += step) {
                        int cx = icx + dx;
                        if (cx < 0 || cx >= GC) continue;
                        int cid = (cz * GC + cy) * GC + cx;
                        int e = min(counts[cid], CAPR);
                        for (int s = 0; s < e; ++s)
                            eval_candidate(rbuck[cid * CAPR + s],
                                           qx, qy, qz, qsq,
                                           bd0, bd1, bd2, bi0, bi1, bi2);
                    }
                }
            }
            float Rr = cert_radius(qx, qy, qz, icx, icy, icz, rho);
            if (bd2 + MARGIN <= Rr * Rr) break;
        }
    }

    epilogue_store(bd0, bd1, bd2, bi0, bi1, bi2, qi, C, point1, out);
}

extern "C" void kernel_launch(void* const* d_in, const int* in_sizes, int n_in,
                              void* d_out, int out_size, void* d_ws, size_t ws_size,
                              hipStream_t stream) {
    const float* xyz1   = (const float*)d_in[0];
    const float* point1 = (const float*)d_in[1];
    const float* xyz2   = (const float*)d_in[2];
    const float* motion = (const float*)d_in[3];
    float* out = (float*)d_out;

    const int n1 = in_sizes[0] / 3;
    const int n2 = in_sizes[2] / 3;
    const int C  = in_sizes[1] / n1;
    const int nq = n2 * C;

    // ws layout (~1.4 MB): rbuck | refspill | zero-zone(counts, rsn)
    char* ws = (char*)d_ws;
    size_t off = 0;
    auto alloc = [&](size_t bytes) {
        char* p = ws + off;
        off = (off + bytes + 255) & ~(size_t)255;
        return p;
    };
    float4* rbuck    = (float4*)alloc((size_t)NCELLS * CAPR * 16);
    float4* refspill = (float4*)alloc((size_t)n1 * 16);
    int*    zero     = (int*)alloc((size_t)(NCELLS + 1) * 4);
    int* counts = zero;
    int* rsn    = zero + NCELLS;

    hipMemsetAsync(zero, 0, (size_t)(NCELLS + 1) * 4, stream);
    scatter_ref_kernel<<<(n1 + 255) / 256, 256, 0, stream>>>(
        xyz1, n1, counts, rbuck, refspill, rsn);
    knn_query_kernel<<<(nq + 255) / 256, 256, 0, stream>>>(
        xyz2, motion, rbuck, counts, refspill, rsn, point1, out, nq, C);
}